// Round 1
// baseline (1090.543 us; speedup 1.0000x reference)
//
#include <hip/hip_runtime.h>
#include <hip/hip_bf16.h>

typedef __bf16 bf8 __attribute__((ext_vector_type(8)));
typedef __bf16 bfx4 __attribute__((ext_vector_type(4)));
typedef float f4 __attribute__((ext_vector_type(4)));

#define NTOK 9216
#define CDIM 256
#define QS 8          // q-split for stats pass
#define QCHUNK 1152   // NTOK/QS
#define KSPLIT 2
#define KHALF 4608    // NTOK/KSPLIT

// ---- MFMA fragment helpers (16x16x32 bf16) --------------------------------
// A[m][k]: lane m=l&15, k=(l>>4)*8+j ; Bt[n][k] same addressing ; D: col=l&15,
// row=(l>>4)*4+reg  [verified layouts per m89/m120]
__device__ inline bf8 ldfrag(const __bf16* p, int ld) {
  int l = threadIdx.x & 63;
  return *reinterpret_cast<const bf8*>(p + (l & 15) * ld + ((l >> 4) << 3));
}
__device__ inline f4 mfma16(bf8 a, bf8 b, f4 c) {
  return __builtin_amdgcn_mfma_f32_16x16x32_bf16(a, b, c, 0, 0, 0);
}

// ---- prep: bf16 weight copies, rel gather, Wproj split --------------------
__global__ __launch_bounds__(256) void prep_kernel(
    const float* Wq, const float* Wk, const float* Wv, const float* embd,
    const float* Wproj, const int* dist, const int* isWithin,
    __bf16* Wqb, __bf16* Wkb, __bf16* Wvb, __bf16* Wpb, float* wl, __bf16* rel) {
  int tid = blockIdx.x * 256 + threadIdx.x;
  if (tid < 65536) {
    Wqb[tid] = (__bf16)Wq[tid];
    Wkb[tid] = (__bf16)Wk[tid];
    Wvb[tid] = (__bf16)Wv[tid];
    int o = tid >> 8, c = tid & 255;
    Wpb[tid] = (__bf16)Wproj[o * 257 + c];
    if (c == 0) wl[o] = Wproj[o * 257 + 256];
  }
  if (tid < 16 * 256) {
    int z = tid >> 8, c = tid & 255;
    int iw = isWithin[z];
    int dd = dist[z] + 8;
    rel[tid] = (__bf16)embd[(iw * 17 + dd) * 256 + c];
  }
}

// ---- transpose x [C,N] f32 -> Xt [N,C] bf16 -------------------------------
__global__ __launch_bounds__(256) void transpose_kernel(const float* x, __bf16* Xt) {
  __shared__ __bf16 tile[32][33];
  int n0 = blockIdx.x * 32;
  int c0 = blockIdx.y * 32;
  int tx = threadIdx.x & 31, ty = threadIdx.x >> 5;
  for (int i = 0; i < 32; i += 8)
    tile[ty + i][tx] = (__bf16)x[(c0 + ty + i) * NTOK + n0 + tx];
  __syncthreads();
  for (int i = 0; i < 32; i += 8)
    Xt[(n0 + ty + i) * CDIM + c0 + tx] = tile[tx][ty + i];
}

// ---- Qt/Kt: Ot[N,256] = Xt[N,256] x Wb[256,256]^T -------------------------
__global__ __launch_bounds__(256) void gemm_qk(const __bf16* Xt, const __bf16* Wb,
                                               __bf16* Ot) {
  int r0 = blockIdx.x * 64;
  int c0 = (threadIdx.x >> 6) * 64;
  f4 acc[4][4] = {};
  for (int ks = 0; ks < 256; ks += 32) {
    bf8 a[4], b[4];
    for (int i = 0; i < 4; i++) a[i] = ldfrag(Xt + (r0 + 16 * i) * 256 + ks, 256);
    for (int j = 0; j < 4; j++) b[j] = ldfrag(Wb + (c0 + 16 * j) * 256 + ks, 256);
    for (int i = 0; i < 4; i++)
      for (int j = 0; j < 4; j++) acc[i][j] = mfma16(a[i], b[j], acc[i][j]);
  }
  int l = threadIdx.x & 63, lc = l & 15, quad = l >> 4;
  for (int i = 0; i < 4; i++)
    for (int j = 0; j < 4; j++)
      for (int r = 0; r < 4; r++)
        Ot[(r0 + 16 * i + quad * 4 + r) * 256 + c0 + 16 * j + lc] = (__bf16)acc[i][j][r];
}

// ---- out[256,9216] = A[256,256] x Bt[9216,256]^T (V and base) -------------
template <typename OutT>
__global__ __launch_bounds__(256) void gemm_256N(const __bf16* A, const __bf16* Bt,
                                                 OutT* out) {
  int c0 = blockIdx.y * 64;
  int n0 = blockIdx.x * 256 + (threadIdx.x >> 6) * 64;
  f4 acc[4][4] = {};
  for (int ks = 0; ks < 256; ks += 32) {
    bf8 a[4], b[4];
    for (int i = 0; i < 4; i++) a[i] = ldfrag(A + (c0 + 16 * i) * 256 + ks, 256);
    for (int j = 0; j < 4; j++) b[j] = ldfrag(Bt + (n0 + 16 * j) * 256 + ks, 256);
    for (int i = 0; i < 4; i++)
      for (int j = 0; j < 4; j++) acc[i][j] = mfma16(a[i], b[j], acc[i][j]);
  }
  int l = threadIdx.x & 63, lc = l & 15, quad = l >> 4;
  for (int i = 0; i < 4; i++)
    for (int j = 0; j < 4; j++)
      for (int r = 0; r < 4; r++)
        out[(c0 + 16 * i + quad * 4 + r) * NTOK + n0 + 16 * j + lc] =
            (OutT)acc[i][j][r];
}

// ---- pos[16,9216] f32 = rel[16,256] x Xt[9216,256]^T ----------------------
__global__ __launch_bounds__(256) void gemm_pos(const __bf16* rel, const __bf16* Xt,
                                                float* pos) {
  int n0 = blockIdx.x * 256 + (threadIdx.x >> 6) * 64;
  f4 acc[4] = {};
  for (int ks = 0; ks < 256; ks += 32) {
    bf8 a = ldfrag(rel + ks, 256);
    for (int j = 0; j < 4; j++) {
      bf8 b = ldfrag(Xt + (n0 + 16 * j) * 256 + ks, 256);
      acc[j] = mfma16(a, b, acc[j]);
    }
  }
  int l = threadIdx.x & 63, lc = l & 15, quad = l >> 4;
  for (int j = 0; j < 4; j++)
    for (int r = 0; r < 4; r++)
      pos[(quad * 4 + r) * NTOK + n0 + 16 * j + lc] = acc[j][r];
}

// ---- pass A: per-key online softmax stats over q --------------------------
__global__ __launch_bounds__(256) void stats_kernel(const __bf16* Kt, const __bf16* Qt,
                                                    float* mpart, float* dpart) {
  int w = threadIdx.x >> 6;
  int l = threadIdx.x & 63;
  int kb = blockIdx.x * 128 + w * 32;  // this wave's 32 key rows
  int q0 = blockIdx.y * QCHUNK;
  bf8 a[2][8];
  for (int g = 0; g < 2; g++)
    for (int cs = 0; cs < 8; cs++)
      a[g][cs] = ldfrag(Kt + (kb + 16 * g) * 256 + cs * 32, 256);
  float mr[2][4], dr[2][4];
  for (int g = 0; g < 2; g++)
    for (int r = 0; r < 4; r++) { mr[g][r] = -1e30f; dr[g][r] = 0.f; }
  for (int q = q0; q < q0 + QCHUNK; q += 16) {
    f4 s0 = {0.f, 0.f, 0.f, 0.f}, s1 = {0.f, 0.f, 0.f, 0.f};
    for (int cs = 0; cs < 8; cs++) {
      bf8 b = ldfrag(Qt + q * 256 + cs * 32, 256);
      s0 = mfma16(a[0][cs], b, s0);
      s1 = mfma16(a[1][cs], b, s1);
    }
    for (int r = 0; r < 4; r++) {
      float s = s0[r], mo = mr[0][r], mn = fmaxf(mo, s);
      dr[0][r] = dr[0][r] * __expf(mo - mn) + __expf(s - mn);
      mr[0][r] = mn;
      s = s1[r]; mo = mr[1][r]; mn = fmaxf(mo, s);
      dr[1][r] = dr[1][r] * __expf(mo - mn) + __expf(s - mn);
      mr[1][r] = mn;
    }
  }
  for (int g = 0; g < 2; g++)
    for (int r = 0; r < 4; r++) {
      float mv = mr[g][r], dv = dr[g][r];
      for (int off = 1; off < 16; off <<= 1) {
        float mo = __shfl_xor(mv, off);
        float dn = __shfl_xor(dv, off);
        float mn = fmaxf(mv, mo);
        dv = dv * __expf(mv - mn) + dn * __expf(mo - mn);
        mv = mn;
      }
      if ((l & 15) == 0) {
        int k = kb + 16 * g + (l >> 4) * 4 + r;
        mpart[blockIdx.y * NTOK + k] = mv;
        dpart[blockIdx.y * NTOK + k] = dv;
      }
    }
}

__global__ __launch_bounds__(256) void stats_combine_kernel(const float* mpart,
                                                            const float* dpart,
                                                            float* mOut, float* dinvOut) {
  int k = blockIdx.x * 256 + threadIdx.x;
  float mm = -1e30f;
  for (int s = 0; s < QS; s++) mm = fmaxf(mm, mpart[s * NTOK + k]);
  float d = 0.f;
  for (int s = 0; s < QS; s++) d += dpart[s * NTOK + k] * __expf(mpart[s * NTOK + k] - mm);
  mOut[k] = mm;
  dinvOut[k] = 1.0f / d;
}

// ---- pass B: Y^T[q,c] partials = sum_k P[k,q] V[c,k] ----------------------
__global__ __launch_bounds__(256) void attn_pv_kernel(const __bf16* Kt, const __bf16* Qt,
                                                      const __bf16* V, const float* m,
                                                      const float* dinv, float* Ypart) {
  __shared__ __bf16 Pt[64][40];  // [q_local][k_local], padded ld=40 (2-way free)
  int w = threadIdx.x >> 6;
  int l = threadIdx.x & 63;
  int lc = l & 15, quad = l >> 4;
  int q0 = blockIdx.x * 64;
  int kz0 = blockIdx.y * KHALF;

  bf8 qf[8];  // wave's Qt rows [q0+16w, +16) x full C, persistent
  for (int cs = 0; cs < 8; cs++)
    qf[cs] = ldfrag(Qt + (q0 + 16 * w) * 256 + cs * 32, 256);

  f4 Yacc[4][4] = {};  // [qgroup][cgroup]; wave's c range = 64w

  for (int kk = kz0; kk < kz0 + KHALF; kk += 32) {
    // stage 1: S[kk..kk+32][wave's 16 q]  (bit-identical to pass A order)
    f4 s0 = {0.f, 0.f, 0.f, 0.f}, s1 = {0.f, 0.f, 0.f, 0.f};
    for (int cs = 0; cs < 8; cs++) {
      bf8 a0 = ldfrag(Kt + kk * 256 + cs * 32, 256);
      bf8 a1 = ldfrag(Kt + (kk + 16) * 256 + cs * 32, 256);
      s0 = mfma16(a0, qf[cs], s0);
      s1 = mfma16(a1, qf[cs], s1);
    }
    int qcol = 16 * w + lc;
    {
      bfx4 p0, p1;
      for (int r = 0; r < 4; r++) {
        int kg = kk + quad * 4 + r;
        p0[r] = (__bf16)(__expf(s0[r] - m[kg]) * dinv[kg]);
        kg += 16;
        p1[r] = (__bf16)(__expf(s1[r] - m[kg]) * dinv[kg]);
      }
      *reinterpret_cast<bfx4*>(&Pt[qcol][quad * 4]) = p0;
      *reinterpret_cast<bfx4*>(&Pt[qcol][16 + quad * 4]) = p1;
    }
    __syncthreads();
    // stage 2: Yacc += Pt(A-op) x V(B-op)
    bf8 vb[4];
    for (int j = 0; j < 4; j++)
      vb[j] = ldfrag(V + (64 * w + 16 * j) * NTOK + kk, NTOK);
    for (int i = 0; i < 4; i++) {
      bf8 pa = *reinterpret_cast<const bf8*>(&Pt[16 * i + lc][quad * 8]);
      for (int j = 0; j < 4; j++) Yacc[i][j] = mfma16(pa, vb[j], Yacc[i][j]);
    }
    __syncthreads();
  }
  float* Yp = Ypart + (size_t)blockIdx.y * (NTOK * 256);
  for (int i = 0; i < 4; i++)
    for (int j = 0; j < 4; j++)
      for (int r = 0; r < 4; r++)
        Yp[(q0 + 16 * i + quad * 4 + r) * 256 + 64 * w + 16 * j + lc] = Yacc[i][j][r];
}

// ---- combine Y halves + residual -> outT [N,C] bf16 -----------------------
__global__ __launch_bounds__(256) void combine_y_kernel(const float* Ypart,
                                                        const __bf16* Xt, __bf16* outT) {
  int i = blockIdx.x * 256 + threadIdx.x;  // over 589824 groups of 4
  f4 y0 = reinterpret_cast<const f4*>(Ypart)[i];
  f4 y1 = reinterpret_cast<const f4*>(Ypart + (size_t)NTOK * 256)[i];
  bfx4 xv = reinterpret_cast<const bfx4*>(Xt)[i];
  bfx4 o;
  for (int t = 0; t < 4; t++) o[t] = (__bf16)(y0[t] + y1[t] + (float)xv[t]);
  reinterpret_cast<bfx4*>(outT)[i] = o;
}

// ---- final: out[z,o,n] = base[o,n] + wl[o]*pos[z,n] -----------------------
__global__ __launch_bounds__(256) void final_kernel(const float* base, const float* pos,
                                                    const float* wl, float* out) {
  int i = blockIdx.x * 256 + threadIdx.x;  // over 9,437,184 f32x4 groups
  int n4 = i % 2304;
  int t = i / 2304;
  int o = t & 255;
  int z = t >> 8;
  f4 b = reinterpret_cast<const f4*>(base)[o * 2304 + n4];
  f4 p = reinterpret_cast<const f4*>(pos)[z * 2304 + n4];
  float ww = wl[o];
  f4 r;
  for (int u = 0; u < 4; u++) r[u] = b[u] + ww * p[u];
  reinterpret_cast<f4*>(out)[i] = r;
}

extern "C" void kernel_launch(void* const* d_in, const int* in_sizes, int n_in,
                              void* d_out, int out_size, void* d_ws, size_t ws_size,
                              hipStream_t stream) {
  const float* x = (const float*)d_in[0];
  const float* Wq = (const float*)d_in[1];
  const float* Wk = (const float*)d_in[2];
  const float* Wv = (const float*)d_in[3];
  const float* embd = (const float*)d_in[4];
  const float* Wproj = (const float*)d_in[5];
  const int* dist = (const int*)d_in[6];
  const int* isW = (const int*)d_in[7];
  float* out = (float*)d_out;

  char* w8 = (char*)d_ws;
  __bf16* Xt = (__bf16*)(w8 + 0);
  __bf16* Qt = (__bf16*)(w8 + 4718592);
  __bf16* Kt = (__bf16*)(w8 + 9437184);
  __bf16* V = (__bf16*)(w8 + 14155776);
  __bf16* Wqb = (__bf16*)(w8 + 18874368);
  __bf16* Wkb = (__bf16*)(w8 + 19005440);
  __bf16* Wvb = (__bf16*)(w8 + 19136512);
  __bf16* Wpb = (__bf16*)(w8 + 19267584);
  __bf16* rel = (__bf16*)(w8 + 19398656);
  float* wl = (float*)(w8 + 19406848);
  float* pos = (float*)(w8 + 19407872);
  float* mpart = (float*)(w8 + 19997696);
  float* dpart = (float*)(w8 + 20292608);
  float* mArr = (float*)(w8 + 20587520);
  float* dinv = (float*)(w8 + 20624384);
  float* Ypart = (float*)(w8 + 20661248);
  __bf16* outT = (__bf16*)(w8 + 39535616);
  float* base = (float*)(w8 + 44254208);
  // total ws use: 53,691,392 bytes

  prep_kernel<<<256, 256, 0, stream>>>(Wq, Wk, Wv, embd, Wproj, dist, isW, Wqb, Wkb,
                                       Wvb, Wpb, wl, rel);
  transpose_kernel<<<dim3(288, 8), 256, 0, stream>>>(x, Xt);
  gemm_qk<<<144, 256, 0, stream>>>(Xt, Wqb, Qt);
  gemm_qk<<<144, 256, 0, stream>>>(Xt, Wkb, Kt);
  gemm_256N<__bf16><<<dim3(36, 4), 256, 0, stream>>>(Wvb, Xt, V);
  gemm_pos<<<36, 256, 0, stream>>>(rel, Xt, pos);
  stats_kernel<<<dim3(72, QS), 256, 0, stream>>>(Kt, Qt, mpart, dpart);
  stats_combine_kernel<<<36, 256, 0, stream>>>(mpart, dpart, mArr, dinv);
  attn_pv_kernel<<<dim3(144, KSPLIT), 256, 0, stream>>>(Kt, Qt, V, mArr, dinv, Ypart);
  combine_y_kernel<<<2304, 256, 0, stream>>>(Ypart, Xt, outT);
  gemm_256N<float><<<dim3(36, 4), 256, 0, stream>>>(Wpb, outT, base);
  final_kernel<<<36864, 256, 0, stream>>>(base, pos, wl, out);
}

// Round 2
// 1002.924 us; speedup vs baseline: 1.0874x; 1.0874x over previous
//
#include <hip/hip_runtime.h>
#include <hip/hip_bf16.h>

typedef __bf16 bf8 __attribute__((ext_vector_type(8)));
typedef __bf16 bfx4 __attribute__((ext_vector_type(4)));
typedef float f4 __attribute__((ext_vector_type(4)));

#define NTOK 9216
#define CDIM 256
#define QS 16         // q-split for stats pass
#define QCHUNK 576    // NTOK/QS
#define KSPLIT 8
#define KCHUNK 1152   // NTOK/KSPLIT
#define LOG2E 1.44269504f

// ---- MFMA fragment helpers (16x16x32 bf16) --------------------------------
// A[m][k]: lane m=l&15, k=(l>>4)*8+j ; Bt[n][k] same addressing ; D: col=l&15,
// row=(l>>4)*4+reg  [verified layouts per m89/m120]
__device__ inline bf8 ldfrag(const __bf16* p, int ld) {
  int l = threadIdx.x & 63;
  return *reinterpret_cast<const bf8*>(p + (l & 15) * ld + ((l >> 4) << 3));
}
__device__ inline f4 mfma16(bf8 a, bf8 b, f4 c) {
  return __builtin_amdgcn_mfma_f32_16x16x32_bf16(a, b, c, 0, 0, 0);
}

// ---- prep: bf16 weight copies (Wq pre-scaled by log2e), rel gather --------
__global__ __launch_bounds__(256) void prep_kernel(
    const float* Wq, const float* Wk, const float* Wv, const float* embd,
    const float* Wproj, const int* dist, const int* isWithin,
    __bf16* Wqb, __bf16* Wkb, __bf16* Wvb, __bf16* Wpb, float* wl, __bf16* rel) {
  int tid = blockIdx.x * 256 + threadIdx.x;
  if (tid < 65536) {
    Wqb[tid] = (__bf16)(Wq[tid] * LOG2E);  // exp2 domain for softmax
    Wkb[tid] = (__bf16)Wk[tid];
    Wvb[tid] = (__bf16)Wv[tid];
    int o = tid >> 8, c = tid & 255;
    Wpb[tid] = (__bf16)Wproj[o * 257 + c];
    if (c == 0) wl[o] = Wproj[o * 257 + 256];
  }
  if (tid < 16 * 256) {
    int z = tid >> 8, c = tid & 255;
    int iw = isWithin[z];
    int dd = dist[z] + 8;
    rel[tid] = (__bf16)embd[(iw * 17 + dd) * 256 + c];
  }
}

// ---- transpose x [C,N] f32 -> Xt [N,C] bf16 -------------------------------
__global__ __launch_bounds__(256) void transpose_kernel(const float* x, __bf16* Xt) {
  __shared__ __bf16 tile[32][33];
  int n0 = blockIdx.x * 32;
  int c0 = blockIdx.y * 32;
  int tx = threadIdx.x & 31, ty = threadIdx.x >> 5;
  for (int i = 0; i < 32; i += 8)
    tile[ty + i][tx] = (__bf16)x[(c0 + ty + i) * NTOK + n0 + tx];
  __syncthreads();
  for (int i = 0; i < 32; i += 8)
    Xt[(n0 + ty + i) * CDIM + c0 + tx] = tile[tx][ty + i];
}

// ---- Qt/Kt: Ot[N,256] = Xt[N,256] x Wb[256,256]^T -------------------------
__global__ __launch_bounds__(256) void gemm_qk(const __bf16* Xt, const __bf16* Wb,
                                               __bf16* Ot) {
  int r0 = blockIdx.x * 64;
  int c0 = (threadIdx.x >> 6) * 64;
  f4 acc[4][4] = {};
  for (int ks = 0; ks < 256; ks += 32) {
    bf8 a[4], b[4];
    for (int i = 0; i < 4; i++) a[i] = ldfrag(Xt + (r0 + 16 * i) * 256 + ks, 256);
    for (int j = 0; j < 4; j++) b[j] = ldfrag(Wb + (c0 + 16 * j) * 256 + ks, 256);
    for (int i = 0; i < 4; i++)
      for (int j = 0; j < 4; j++) acc[i][j] = mfma16(a[i], b[j], acc[i][j]);
  }
  int l = threadIdx.x & 63, lc = l & 15, quad = l >> 4;
  for (int i = 0; i < 4; i++)
    for (int j = 0; j < 4; j++)
      for (int r = 0; r < 4; r++)
        Ot[(r0 + 16 * i + quad * 4 + r) * 256 + c0 + 16 * j + lc] = (__bf16)acc[i][j][r];
}

// ---- out[256,9216] = A[256,256] x Bt[9216,256]^T (V and base) -------------
template <typename OutT>
__global__ __launch_bounds__(256) void gemm_256N(const __bf16* A, const __bf16* Bt,
                                                 OutT* out) {
  int c0 = blockIdx.y * 64;
  int n0 = blockIdx.x * 256 + (threadIdx.x >> 6) * 64;
  f4 acc[4][4] = {};
  for (int ks = 0; ks < 256; ks += 32) {
    bf8 a[4], b[4];
    for (int i = 0; i < 4; i++) a[i] = ldfrag(A + (c0 + 16 * i) * 256 + ks, 256);
    for (int j = 0; j < 4; j++) b[j] = ldfrag(Bt + (n0 + 16 * j) * 256 + ks, 256);
    for (int i = 0; i < 4; i++)
      for (int j = 0; j < 4; j++) acc[i][j] = mfma16(a[i], b[j], acc[i][j]);
  }
  int l = threadIdx.x & 63, lc = l & 15, quad = l >> 4;
  for (int i = 0; i < 4; i++)
    for (int j = 0; j < 4; j++)
      for (int r = 0; r < 4; r++)
        out[(c0 + 16 * i + quad * 4 + r) * NTOK + n0 + 16 * j + lc] =
            (OutT)acc[i][j][r];
}

// ---- pos[16,9216] f32 = rel[16,256] x Xt[9216,256]^T ----------------------
__global__ __launch_bounds__(256) void gemm_pos(const __bf16* rel, const __bf16* Xt,
                                                float* pos) {
  int n0 = blockIdx.x * 256 + (threadIdx.x >> 6) * 64;
  f4 acc[4] = {};
  for (int ks = 0; ks < 256; ks += 32) {
    bf8 a = ldfrag(rel + ks, 256);
    for (int j = 0; j < 4; j++) {
      bf8 b = ldfrag(Xt + (n0 + 16 * j) * 256 + ks, 256);
      acc[j] = mfma16(a, b, acc[j]);
    }
  }
  int l = threadIdx.x & 63, lc = l & 15, quad = l >> 4;
  for (int j = 0; j < 4; j++)
    for (int r = 0; r < 4; r++)
      pos[(quad * 4 + r) * NTOK + n0 + 16 * j + lc] = acc[j][r];
}

// ---- zero Y accumulator ---------------------------------------------------
__global__ __launch_bounds__(256) void zero_y_kernel(float* Y) {
  reinterpret_cast<f4*>(Y)[blockIdx.x * 256 + threadIdx.x] = f4{0.f, 0.f, 0.f, 0.f};
}

// ---- pass A: per-key online softmax stats over q (exp2 domain) ------------
// wave handles 16 keys; q unrolled x4 -> 4 independent MFMA chains; one
// rescale per 4 scores of a key (chunk max).
__global__ __launch_bounds__(256) void stats_kernel(const __bf16* Kt, const __bf16* Qt,
                                                    float* mpart, float* dpart) {
  int w = threadIdx.x >> 6;
  int l = threadIdx.x & 63;
  int lc = l & 15, quad = l >> 4;
  int kb = blockIdx.x * 64 + w * 16;  // this wave's 16 key rows
  int q0 = blockIdx.y * QCHUNK;
  bf8 a[8];
  for (int cs = 0; cs < 8; cs++)
    a[cs] = ldfrag(Kt + kb * 256 + cs * 32, 256);
  float mr[4], dr[4];
  for (int r = 0; r < 4; r++) { mr[r] = -1e30f; dr[r] = 0.f; }
  for (int q = q0; q < q0 + QCHUNK; q += 64) {
    f4 s[4] = {};
    for (int cs = 0; cs < 8; cs++) {
      for (int qq = 0; qq < 4; qq++) {
        bf8 b = ldfrag(Qt + (q + qq * 16) * 256 + cs * 32, 256);
        s[qq] = mfma16(a[cs], b, s[qq]);
      }
    }
    for (int r = 0; r < 4; r++) {
      float cm = fmaxf(fmaxf(s[0][r], s[1][r]), fmaxf(s[2][r], s[3][r]));
      float mo = mr[r];
      float mn = fmaxf(mo, cm);
      float dd = exp2f(s[0][r] - mn) + exp2f(s[1][r] - mn) +
                 exp2f(s[2][r] - mn) + exp2f(s[3][r] - mn);
      dr[r] = dr[r] * exp2f(mo - mn) + dd;
      mr[r] = mn;
    }
  }
  for (int r = 0; r < 4; r++) {
    float mv = mr[r], dv = dr[r];
    for (int off = 1; off < 16; off <<= 1) {
      float mo = __shfl_xor(mv, off);
      float dn = __shfl_xor(dv, off);
      float mn = fmaxf(mv, mo);
      dv = dv * exp2f(mv - mn) + dn * exp2f(mo - mn);
      mv = mn;
    }
    if (lc == 0) {
      int k = kb + quad * 4 + r;
      mpart[blockIdx.y * NTOK + k] = mv;
      dpart[blockIdx.y * NTOK + k] = dv;
    }
  }
}

__global__ __launch_bounds__(256) void stats_combine_kernel(const float* mpart,
                                                            const float* dpart,
                                                            float* mOut, float* dinvOut) {
  int k = blockIdx.x * 256 + threadIdx.x;
  float mm = -1e30f;
  for (int s = 0; s < QS; s++) mm = fmaxf(mm, mpart[s * NTOK + k]);
  float d = 0.f;
  for (int s = 0; s < QS; s++) d += dpart[s * NTOK + k] * exp2f(mpart[s * NTOK + k] - mm);
  mOut[k] = mm;
  dinvOut[k] = 1.0f / d;
}

// ---- pass B: Y[q,c] += sum_k P[k,q] V[c,k] over this block's k-chunk ------
__global__ __launch_bounds__(256) void attn_pv_kernel(const __bf16* Kt, const __bf16* Qt,
                                                      const __bf16* V, const float* m,
                                                      const float* dinv, float* Y) {
  __shared__ __bf16 Pt[64][40];  // [q_local][k_local]
  int w = threadIdx.x >> 6;
  int l = threadIdx.x & 63;
  int lc = l & 15, quad = l >> 4;
  int q0 = blockIdx.x * 64;
  int kz0 = blockIdx.y * KCHUNK;

  bf8 qf[8];  // wave's Qt rows [q0+16w, +16) x full C, persistent
  for (int cs = 0; cs < 8; cs++)
    qf[cs] = ldfrag(Qt + (q0 + 16 * w) * 256 + cs * 32, 256);

  f4 Yacc[4][4] = {};  // [qgroup][cgroup]; wave's c range = 64w

  for (int kk = kz0; kk < kz0 + KCHUNK; kk += 32) {
    // stage 1: S[kk..kk+32][wave's 16 q]  (bit-identical to pass A chains)
    f4 s0 = {0.f, 0.f, 0.f, 0.f}, s1 = {0.f, 0.f, 0.f, 0.f};
    for (int cs = 0; cs < 8; cs++) {
      bf8 a0 = ldfrag(Kt + kk * 256 + cs * 32, 256);
      bf8 a1 = ldfrag(Kt + (kk + 16) * 256 + cs * 32, 256);
      s0 = mfma16(a0, qf[cs], s0);
      s1 = mfma16(a1, qf[cs], s1);
    }
    f4 m0 = *reinterpret_cast<const f4*>(m + kk + quad * 4);
    f4 m1 = *reinterpret_cast<const f4*>(m + kk + 16 + quad * 4);
    f4 di0 = *reinterpret_cast<const f4*>(dinv + kk + quad * 4);
    f4 di1 = *reinterpret_cast<const f4*>(dinv + kk + 16 + quad * 4);
    int qcol = 16 * w + lc;
    {
      bfx4 p0, p1;
      for (int r = 0; r < 4; r++) {
        p0[r] = (__bf16)(exp2f(s0[r] - m0[r]) * di0[r]);
        p1[r] = (__bf16)(exp2f(s1[r] - m1[r]) * di1[r]);
      }
      *reinterpret_cast<bfx4*>(&Pt[qcol][quad * 4]) = p0;
      *reinterpret_cast<bfx4*>(&Pt[qcol][16 + quad * 4]) = p1;
    }
    __syncthreads();
    // stage 2: Yacc += Pt(A-op) x V(B-op)
    bf8 vb[4];
    for (int j = 0; j < 4; j++)
      vb[j] = ldfrag(V + (64 * w + 16 * j) * NTOK + kk, NTOK);
    for (int i = 0; i < 4; i++) {
      bf8 pa = *reinterpret_cast<const bf8*>(&Pt[16 * i + lc][quad * 8]);
      for (int j = 0; j < 4; j++) Yacc[i][j] = mfma16(pa, vb[j], Yacc[i][j]);
    }
    __syncthreads();
  }
  for (int i = 0; i < 4; i++)
    for (int j = 0; j < 4; j++)
      for (int r = 0; r < 4; r++)
        atomicAdd(&Y[(q0 + 16 * i + quad * 4 + r) * 256 + 64 * w + 16 * j + lc],
                  Yacc[i][j][r]);
}

// ---- combine Y + residual -> outT [N,C] bf16 ------------------------------
__global__ __launch_bounds__(256) void combine_y_kernel(const float* Y,
                                                        const __bf16* Xt, __bf16* outT) {
  int i = blockIdx.x * 256 + threadIdx.x;  // over 589824 groups of 4
  f4 y = reinterpret_cast<const f4*>(Y)[i];
  bfx4 xv = reinterpret_cast<const bfx4*>(Xt)[i];
  bfx4 o;
  for (int t = 0; t < 4; t++) o[t] = (__bf16)(y[t] + (float)xv[t]);
  reinterpret_cast<bfx4*>(outT)[i] = o;
}

// ---- final: out[z,o,n] = base[o,n] + wl[o]*pos[z,n] -----------------------
__global__ __launch_bounds__(256) void final_kernel(const float* base, const float* pos,
                                                    const float* wl, float* out) {
  int i = blockIdx.x * 256 + threadIdx.x;  // over 9,437,184 f32x4 groups
  int n4 = i % 2304;
  int t = i / 2304;
  int o = t & 255;
  int z = t >> 8;
  f4 b = reinterpret_cast<const f4*>(base)[o * 2304 + n4];
  f4 p = reinterpret_cast<const f4*>(pos)[z * 2304 + n4];
  float ww = wl[o];
  f4 r;
  for (int u = 0; u < 4; u++) r[u] = b[u] + ww * p[u];
  reinterpret_cast<f4*>(out)[i] = r;
}

extern "C" void kernel_launch(void* const* d_in, const int* in_sizes, int n_in,
                              void* d_out, int out_size, void* d_ws, size_t ws_size,
                              hipStream_t stream) {
  const float* x = (const float*)d_in[0];
  const float* Wq = (const float*)d_in[1];
  const float* Wk = (const float*)d_in[2];
  const float* Wv = (const float*)d_in[3];
  const float* embd = (const float*)d_in[4];
  const float* Wproj = (const float*)d_in[5];
  const int* dist = (const int*)d_in[6];
  const int* isW = (const int*)d_in[7];
  float* out = (float*)d_out;

  char* w8 = (char*)d_ws;
  __bf16* Xt = (__bf16*)(w8 + 0);
  __bf16* Qt = (__bf16*)(w8 + 4718592);
  __bf16* Kt = (__bf16*)(w8 + 9437184);
  __bf16* V = (__bf16*)(w8 + 14155776);
  __bf16* Wqb = (__bf16*)(w8 + 18874368);
  __bf16* Wkb = (__bf16*)(w8 + 19005440);
  __bf16* Wvb = (__bf16*)(w8 + 19136512);
  __bf16* Wpb = (__bf16*)(w8 + 19267584);
  __bf16* rel = (__bf16*)(w8 + 19398656);
  float* wl = (float*)(w8 + 19406848);
  float* pos = (float*)(w8 + 19407872);
  float* mpart = (float*)(w8 + 19997696);   // 16*9216*4 = 589,824
  float* dpart = (float*)(w8 + 20587520);   // 589,824
  float* mArr = (float*)(w8 + 21177344);    // 36,864
  float* dinv = (float*)(w8 + 21214208);    // 36,864
  float* Yacc = (float*)(w8 + 21251072);    // 9,437,184
  __bf16* outT = (__bf16*)(w8 + 30688256);  // 4,718,592
  float* base = (float*)(w8 + 35406848);    // 9,437,184
  // total ws use: 44,844,032 bytes

  prep_kernel<<<256, 256, 0, stream>>>(Wq, Wk, Wv, embd, Wproj, dist, isW, Wqb, Wkb,
                                       Wvb, Wpb, wl, rel);
  transpose_kernel<<<dim3(288, 8), 256, 0, stream>>>(x, Xt);
  gemm_qk<<<144, 256, 0, stream>>>(Xt, Wqb, Qt);
  gemm_qk<<<144, 256, 0, stream>>>(Xt, Wkb, Kt);
  gemm_256N<__bf16><<<dim3(36, 4), 256, 0, stream>>>(Wvb, Xt, V);
  gemm_pos<<<36, 256, 0, stream>>>(rel, Xt, pos);
  zero_y_kernel<<<2304, 256, 0, stream>>>(Yacc);
  stats_kernel<<<dim3(144, QS), 256, 0, stream>>>(Kt, Qt, mpart, dpart);
  stats_combine_kernel<<<36, 256, 0, stream>>>(mpart, dpart, mArr, dinv);
  attn_pv_kernel<<<dim3(144, KSPLIT), 256, 0, stream>>>(Kt, Qt, V, mArr, dinv, Yacc);
  combine_y_kernel<<<2304, 256, 0, stream>>>(Yacc, Xt, outT);
  gemm_256N<float><<<dim3(36, 4), 256, 0, stream>>>(Wpb, outT, base);
  final_kernel<<<36864, 256, 0, stream>>>(base, pos, wl, out);
}

// Round 3
// 594.100 us; speedup vs baseline: 1.8356x; 1.6881x over previous
//
#include <hip/hip_runtime.h>
#include <hip/hip_bf16.h>

typedef __bf16 bf8 __attribute__((ext_vector_type(8)));
typedef __bf16 bfx4 __attribute__((ext_vector_type(4)));
typedef float f4 __attribute__((ext_vector_type(4)));

#define NTOK 9216
#define CDIM 256
#define LOG2E 1.44269504f

// ---- MFMA fragment helpers (16x16x32 bf16) --------------------------------
// A[m][k]: lane m=l&15, k=(l>>4)*8+j ; Bt[n][k] same ; D: row=(l>>4)*4+reg,
// col=l&15  [verified by R1/R2 passing]
__device__ inline bf8 ldfrag(const __bf16* p, int ld) {
  int l = threadIdx.x & 63;
  return *reinterpret_cast<const bf8*>(p + (l & 15) * ld + ((l >> 4) << 3));
}
__device__ inline f4 mfma16(bf8 a, bf8 b, f4 c) {
  return __builtin_amdgcn_mfma_f32_16x16x32_bf16(a, b, c, 0, 0, 0);
}
// async global->LDS, 16B per lane; LDS dest = base + lane*16 (wave-uniform base)
__device__ inline void gl2lds(const __bf16* g, __bf16* l) {
  __builtin_amdgcn_global_load_lds(
      (const __attribute__((address_space(1))) void*)g,
      (__attribute__((address_space(3))) void*)l, 16, 0, 0);
}

// ---- generic m97-style GEMM: C[M][N] = A[M][K](lda) x Bt[N][K](ldb)^T ------
// 128x128 tile, BK=32, 4 waves in 2x2. blockIdx.z = split-K part (adds z*K to
// the k offset of both A and Bt; caller passes K = per-part k count).
// EPI: 0 = store fp32, 1 = store bf16, 2 = atomicAdd fp32
template <int EPI>
__global__ __launch_bounds__(256) void gemm128(const __bf16* __restrict__ A, int lda,
                                               const __bf16* __restrict__ Bt, int ldb,
                                               void* __restrict__ Cv, int ldc, int K) {
  __shared__ __bf16 As[128 * 32];
  __shared__ __bf16 Bs[128 * 32];
  const int tid = threadIdx.x;
  const int w = tid >> 6, lane = tid & 63;
  const int lc = lane & 15, quad = lane >> 4;
  const int m0 = blockIdx.x * 128, n0 = blockIdx.y * 128;
  A += (size_t)blockIdx.z * K;
  Bt += (size_t)blockIdx.z * K;
  const int wm = (w & 1) << 6, wn = (w >> 1) << 6;
  // staging: wave w fills LDS chunks 2w, 2w+1 of A and B (16 rows x 32k each)
  const int r0 = (w * 2) * 16 + (lane >> 2);
  const int cg = (lane & 3) * 8;
  const __bf16* gA0 = A + (size_t)(m0 + r0) * lda + cg;
  const __bf16* gA1 = A + (size_t)(m0 + r0 + 16) * lda + cg;
  const __bf16* gB0 = Bt + (size_t)(n0 + r0) * ldb + cg;
  const __bf16* gB1 = Bt + (size_t)(n0 + r0 + 16) * ldb + cg;
  __bf16* lA0 = As + (w * 2) * 512;
  __bf16* lA1 = As + (w * 2 + 1) * 512;
  __bf16* lB0 = Bs + (w * 2) * 512;
  __bf16* lB1 = Bs + (w * 2 + 1) * 512;

  f4 acc[4][4] = {};
  for (int kk = 0; kk < K; kk += 32) {
    __syncthreads();
    gl2lds(gA0 + kk, lA0);
    gl2lds(gA1 + kk, lA1);
    gl2lds(gB0 + kk, lB0);
    gl2lds(gB1 + kk, lB1);
    __syncthreads();  // compiler drains vmcnt before s_barrier
    bf8 af[4], bfr[4];
    for (int i = 0; i < 4; i++) af[i] = ldfrag(As + (wm + 16 * i) * 32, 32);
    for (int j = 0; j < 4; j++) bfr[j] = ldfrag(Bs + (wn + 16 * j) * 32, 32);
    for (int i = 0; i < 4; i++)
      for (int j = 0; j < 4; j++) acc[i][j] = mfma16(af[i], bfr[j], acc[i][j]);
  }
  for (int i = 0; i < 4; i++)
    for (int j = 0; j < 4; j++)
      for (int r = 0; r < 4; r++) {
        size_t idx = (size_t)(m0 + wm + 16 * i + quad * 4 + r) * ldc +
                     (n0 + wn + 16 * j + lc);
        if (EPI == 0) ((float*)Cv)[idx] = acc[i][j][r];
        else if (EPI == 1) ((__bf16*)Cv)[idx] = (__bf16)acc[i][j][r];
        else atomicAdd(((float*)Cv) + idx, acc[i][j][r]);
      }
}

// ---- prep: bf16 weights (Wq pre-scaled by log2e, fused QK), rel gather ----
__global__ __launch_bounds__(256) void prep_kernel(
    const float* Wq, const float* Wk, const float* Wv, const float* embd,
    const float* Wproj, const int* dist, const int* isWithin,
    __bf16* Wqkb, __bf16* Wvb, __bf16* Wpb, float* wl, __bf16* rel) {
  int tid = blockIdx.x * 256 + threadIdx.x;
  if (tid < 65536) {
    Wqkb[tid] = (__bf16)(Wq[tid] * LOG2E);  // rows 0..255: Q (exp2 domain)
    Wqkb[65536 + tid] = (__bf16)Wk[tid];    // rows 256..511: K
    Wvb[tid] = (__bf16)Wv[tid];
    int o = tid >> 8, c = tid & 255;
    Wpb[tid] = (__bf16)Wproj[o * 257 + c];
    if (c == 0) wl[o] = Wproj[o * 257 + 256];
  }
  if (tid < 16 * 256) {
    int z = tid >> 8, c = tid & 255;
    rel[tid] = (__bf16)embd[(isWithin[z] * 17 + dist[z] + 8) * 256 + c];
  }
}

// ---- transpose x [C,N] f32 -> Xt [N,C] bf16 -------------------------------
__global__ __launch_bounds__(256) void transpose_kernel(const float* x, __bf16* Xt) {
  __shared__ __bf16 tile[32][33];
  int n0 = blockIdx.x * 32;
  int c0 = blockIdx.y * 32;
  int tx = threadIdx.x & 31, ty = threadIdx.x >> 5;
  for (int i = 0; i < 32; i += 8)
    tile[ty + i][tx] = (__bf16)x[(c0 + ty + i) * NTOK + n0 + tx];
  __syncthreads();
  for (int i = 0; i < 32; i += 8)
    Xt[(n0 + ty + i) * CDIM + c0 + tx] = tile[tx][ty + i];
}

// ---- pos[16,9216] f32 = rel[16,256] x Xt[9216,256]^T ----------------------
__global__ __launch_bounds__(256) void gemm_pos(const __bf16* rel, const __bf16* Xt,
                                                float* pos) {
  int n0 = blockIdx.x * 256 + (threadIdx.x >> 6) * 64;
  f4 acc[4] = {};
  for (int ks = 0; ks < 256; ks += 32) {
    bf8 a = ldfrag(rel + ks, 256);
    for (int j = 0; j < 4; j++) {
      bf8 b = ldfrag(Xt + (n0 + 16 * j) * 256 + ks, 256);
      acc[j] = mfma16(a, b, acc[j]);
    }
  }
  int l = threadIdx.x & 63, lc = l & 15, quad = l >> 4;
  for (int j = 0; j < 4; j++)
    for (int r = 0; r < 4; r++)
      pos[(quad * 4 + r) * NTOK + n0 + 16 * j + lc] = acc[j][r];
}

__global__ __launch_bounds__(256) void zero_y_kernel(float* Y) {
  reinterpret_cast<f4*>(Y)[blockIdx.x * 256 + threadIdx.x] = f4{0.f, 0.f, 0.f, 0.f};
}

// ---- per-k-row softmax stats over full q (one block per row) --------------
__global__ __launch_bounds__(256) void stats_kernel(const float* S, int kc0,
                                                    float* mArr, float* dinvArr) {
  const float* row = S + (size_t)blockIdx.x * NTOK;
  int t = threadIdx.x, w = t >> 6;
  f4 v[9];
  for (int i = 0; i < 9; i++) v[i] = reinterpret_cast<const f4*>(row)[t + 256 * i];
  float m = -1e30f;
  for (int i = 0; i < 9; i++)
    for (int j = 0; j < 4; j++) m = fmaxf(m, v[i][j]);
  for (int off = 1; off < 64; off <<= 1) m = fmaxf(m, __shfl_xor(m, off));
  __shared__ float wm_[4], wd_[4];
  if ((t & 63) == 0) wm_[w] = m;
  __syncthreads();
  m = fmaxf(fmaxf(wm_[0], wm_[1]), fmaxf(wm_[2], wm_[3]));
  float d = 0.f;
  for (int i = 0; i < 9; i++)
    for (int j = 0; j < 4; j++) d += exp2f(v[i][j] - m);
  for (int off = 1; off < 64; off <<= 1) d += __shfl_xor(d, off);
  if ((t & 63) == 0) wd_[w] = d;
  __syncthreads();
  if (t == 0) {
    mArr[kc0 + blockIdx.x] = m;
    dinvArr[kc0 + blockIdx.x] = 1.0f / (wd_[0] + wd_[1] + wd_[2] + wd_[3]);
  }
}

// ---- P'[q][klocal] = bf16(exp2(S[klocal][q]-m_k)*dinv_k), 64x64 LDS transp -
__global__ __launch_bounds__(256) void pbuild_kernel(const float* S, const float* mArr,
                                                     const float* dinvArr, int kc0,
                                                     __bf16* Pt, int KC) {
  __shared__ float tile[64][65];
  __shared__ float ms[64], ds[64];
  int q0 = blockIdx.x * 64, k0 = blockIdx.y * 64;
  int t = threadIdx.x;
  if (t < 64) {
    ms[t] = mArr[kc0 + k0 + t];
    ds[t] = dinvArr[kc0 + k0 + t];
  }
  int kr = t >> 4, qc = t & 15;
  for (int it = 0; it < 4; it++) {
    int k = kr + it * 16;
    f4 sv = reinterpret_cast<const f4*>(S + (size_t)(k0 + k) * NTOK + q0)[qc];
    for (int j = 0; j < 4; j++) tile[k][qc * 4 + j] = sv[j];
  }
  __syncthreads();
  int qr = t >> 2, ks = (t & 3) * 16;
  bf8 h0, h1;
  for (int i = 0; i < 8; i++) {
    h0[i] = (__bf16)(exp2f(tile[ks + i][qr] - ms[ks + i]) * ds[ks + i]);
    h1[i] = (__bf16)(exp2f(tile[ks + 8 + i][qr] - ms[ks + 8 + i]) * ds[ks + 8 + i]);
  }
  __bf16* dst = Pt + (size_t)(q0 + qr) * KC + k0 + ks;
  *reinterpret_cast<bf8*>(dst) = h0;
  *reinterpret_cast<bf8*>(dst + 8) = h1;
}

// ---- combine Yt + residual -> outT [N,C] bf16 -----------------------------
__global__ __launch_bounds__(256) void combine_y_kernel(const float* Y,
                                                        const __bf16* Xt, __bf16* outT) {
  int i = blockIdx.x * 256 + threadIdx.x;
  f4 y = reinterpret_cast<const f4*>(Y)[i];
  bfx4 xv = reinterpret_cast<const bfx4*>(Xt)[i];
  bfx4 o;
  for (int t = 0; t < 4; t++) o[t] = (__bf16)(y[t] + (float)xv[t]);
  reinterpret_cast<bfx4*>(outT)[i] = o;
}

// ---- final: out[z,o,n] = base[o,n] + wl[o]*pos[z,n] -----------------------
__global__ __launch_bounds__(256) void final_kernel(const float* base, const float* pos,
                                                    const float* wl, float* out) {
  int i = blockIdx.x * 256 + threadIdx.x;
  int n4 = i % 2304;
  int t = i / 2304;
  int o = t & 255;
  int z = t >> 8;
  f4 b = reinterpret_cast<const f4*>(base)[o * 2304 + n4];
  f4 p = reinterpret_cast<const f4*>(pos)[z * 2304 + n4];
  float ww = wl[o];
  f4 r;
  for (int u = 0; u < 4; u++) r[u] = b[u] + ww * p[u];
  reinterpret_cast<f4*>(out)[i] = r;
}

extern "C" void kernel_launch(void* const* d_in, const int* in_sizes, int n_in,
                              void* d_out, int out_size, void* d_ws, size_t ws_size,
                              hipStream_t stream) {
  const float* x = (const float*)d_in[0];
  const float* Wq = (const float*)d_in[1];
  const float* Wk = (const float*)d_in[2];
  const float* Wv = (const float*)d_in[3];
  const float* embd = (const float*)d_in[4];
  const float* Wproj = (const float*)d_in[5];
  const int* dist = (const int*)d_in[6];
  const int* isW = (const int*)d_in[7];
  float* out = (float*)d_out;

  char* w8 = (char*)d_ws;
  __bf16* Xt = (__bf16*)(w8 + 0);            // 4,718,592
  __bf16* QKt = (__bf16*)(w8 + 4718592);     // 9,437,184 [q][512]: Q|K
  __bf16* V = (__bf16*)(w8 + 14155776);      // 4,718,592 [c][n]
  __bf16* Wqkb = (__bf16*)(w8 + 18874368);   // 262,144
  __bf16* Wvb = (__bf16*)(w8 + 19136512);    // 131,072
  __bf16* Wpb = (__bf16*)(w8 + 19267584);    // 131,072
  __bf16* rel = (__bf16*)(w8 + 19398656);    // 8,192
  float* wl = (float*)(w8 + 19406848);       // 1,024
  float* pos = (float*)(w8 + 19407872);      // 589,824
  float* mArr = (float*)(w8 + 19997696);     // 36,864
  float* dinv = (float*)(w8 + 20034560);     // 36,864
  float* Yt = (float*)(w8 + 20071424);       // 9,437,184 [q][c] fp32
  const size_t sOff = 29508608;
  float* S = (float*)(w8 + sOff);            // KC*36,864

  // adaptive chunk size (ws_size constant across calls -> graph-safe)
  static const int KCS[] = {9216, 4608, 2304, 1152, 768, 384, 256};
  int KC = 0;
  for (int i = 0; i < 7; i++) {
    size_t need = sOff + (size_t)KCS[i] * NTOK * 6;  // S fp32 + P' bf16
    if (need <= ws_size) { KC = KCS[i]; break; }
  }
  __bf16* Pt;
  __bf16* outT;
  float* base;
  if (KC) {
    Pt = (__bf16*)(w8 + sOff + (size_t)KC * NTOK * 4);
    outT = (__bf16*)(w8 + sOff);             // alias S (dead by then); >=14.2MB
    base = (float*)(w8 + sOff + 4718592);
  } else {                                   // guaranteed-fit fallback (~50.7MB)
    KC = 128;
    Pt = (__bf16*)(w8 + sOff + (size_t)KC * NTOK * 4);
    outT = (__bf16*)(w8 + sOff + (size_t)KC * NTOK * 6);
    base = (float*)(w8 + sOff + (size_t)KC * NTOK * 6 + 4718592);
  }
  int zk = 1;
  if (KC >= 2304) zk = KC / 1152;
  else if (KC == 1152 || KC == 768) zk = 2;
  const int NC = NTOK / KC;

  prep_kernel<<<256, 256, 0, stream>>>(Wq, Wk, Wv, embd, Wproj, dist, isW,
                                       Wqkb, Wvb, Wpb, wl, rel);
  transpose_kernel<<<dim3(288, 8), 256, 0, stream>>>(x, Xt);
  // QK fused: QKt[9216][512] = Xt x Wqkb^T
  gemm128<1><<<dim3(72, 4), 256, 0, stream>>>(Xt, 256, Wqkb, 256, QKt, 512, 256);
  // V[256][9216] = Wvb x Xt^T
  gemm128<1><<<dim3(2, 72), 256, 0, stream>>>(Wvb, 256, Xt, 256, V, NTOK, 256);
  gemm_pos<<<36, 256, 0, stream>>>(rel, Xt, pos);
  zero_y_kernel<<<2304, 256, 0, stream>>>(Yt);

  for (int c = 0; c < NC; c++) {
    int kc0 = c * KC;
    // S[klocal][q] = Kt_chunk x Qt^T   (fp32, log2 domain)
    gemm128<0><<<dim3(KC / 128, 72), 256, 0, stream>>>(
        QKt + (size_t)kc0 * 512 + 256, 512, QKt, 512, S, NTOK, 256);
    stats_kernel<<<KC, 256, 0, stream>>>(S, kc0, mArr, dinv);
    pbuild_kernel<<<dim3(144, KC / 64), 256, 0, stream>>>(S, mArr, dinv, kc0, Pt, KC);
    // Yt[q][c] += P' x V_chunk^T  (split-K, fp32 atomics)
    gemm128<2><<<dim3(72, 2, zk), 256, 0, stream>>>(Pt, KC, V + kc0, NTOK, Yt, 256,
                                                    KC / zk);
  }
  combine_y_kernel<<<2304, 256, 0, stream>>>(Yt, Xt, outT);
  // base[o][n] = Wpb x outT^T
  gemm128<0><<<dim3(2, 72), 256, 0, stream>>>(Wpb, 256, outT, 256, base, NTOK, 256);
  final_kernel<<<36864, 256, 0, stream>>>(base, pos, wl, out);
}